// Round 2
// baseline (2838.923 us; speedup 1.0000x reference)
//
#include <hip/hip_runtime.h>
#include <math.h>

#define N_NODES 50000
#define N_EDGES 800000
#define IN_DIM 128
#define HIDDEN 128
#define CLASSES 64

static __device__ __forceinline__ float elu_f(float x) {
    return x > 0.f ? x : (expf(x) - 1.f);
}

static __device__ __forceinline__ void fma4(float4& a, const float4 w, const float s) {
    a.x = fmaf(w.x, s, a.x);
    a.y = fmaf(w.y, s, a.y);
    a.z = fmaf(w.z, s, a.z);
    a.w = fmaf(w.w, s, a.w);
}

// ---------------------------------------------------------------------------
// Aggregation: one wave (64 lanes) per edge; each lane handles 2 consecutive
// floats of the 128-dim row. agg[dst] += x[src]. Uses HW f32 atomics.
// ---------------------------------------------------------------------------
__global__ __launch_bounds__(256) void k_agg(
    const float* __restrict__ x,
    const int* __restrict__ src1, const int* __restrict__ dst1,
    const int* __restrict__ src2, const int* __restrict__ dst2,
    float* __restrict__ agg1, float* __restrict__ agg2)
{
    const int lane = threadIdx.x & 63;
    const int wid  = (blockIdx.x * 256 + threadIdx.x) >> 6;
    const int nw   = (gridDim.x * 256) >> 6;
    for (int e = wid; e < 2 * N_EDGES; e += nw) {
        const int* sp; const int* dp; float* ap; int ei;
        if (e < N_EDGES) { sp = src1; dp = dst1; ap = agg1; ei = e; }
        else             { sp = src2; dp = dst2; ap = agg2; ei = e - N_EDGES; }
        const int s = sp[ei];
        const int d = dp[ei];
        const float2 v = *reinterpret_cast<const float2*>(x + (size_t)s * IN_DIM + lane * 2);
        float* o = ap + (size_t)d * IN_DIM + lane * 2;
        unsafeAtomicAdd(o,     v.x);
        unsafeAtomicAdd(o + 1, v.y);
    }
}

// ---------------------------------------------------------------------------
// Layer 1: x1[v] = elu(a0*((f[v]+agg1[v])@W1^T + b1)) +
//                  elu(a1*((f[v]+agg2[v])@W1^T + b1))
// W1 is [128][128] row-major; staged transposed in LDS (Wt[k][o]).
// Block: 256 threads; 8 nodes per tile; thread = 4 outputs x 1 node x 2 graphs.
// ---------------------------------------------------------------------------
__global__ __launch_bounds__(256) void k_layer1(
    const float* __restrict__ f,
    const float* __restrict__ agg1, const float* __restrict__ agg2,
    const float* __restrict__ W1, const float* __restrict__ b1,
    const float* __restrict__ attn, float* __restrict__ x1)
{
    __shared__ float Wt[IN_DIM][HIDDEN + 4];  // Wt[k][o] = W1[o][k]; pad row to 132 (16B aligned)
    __shared__ float S[16][IN_DIM];           // 8 nodes x 2 graphs; row r = 2*ln + g

    const int t = threadIdx.x;
    for (int i = t; i < HIDDEN * IN_DIM; i += 256) {
        const int o = i >> 7, k = i & 127;
        Wt[k][o] = W1[i];
    }
    const float a0 = attn[0], a1 = attn[1];
    const int o4 = (t & 31) * 4;
    const int ln = t >> 5;  // 0..7
    const float4 bias = *reinterpret_cast<const float4*>(b1 + o4);

    const int ntiles = N_NODES / 8;  // 6250, exact
    for (int tile = blockIdx.x; tile < ntiles; tile += gridDim.x) {
        const int v0 = tile * 8;
        __syncthreads();
        // load S: 8 nodes x 2 graphs x 128 = 2048 floats
        for (int i = t; i < 2048; i += 256) {
            const int r = i >> 7, k = i & 127;
            const int node = v0 + (r >> 1);
            const float* ag = (r & 1) ? agg2 : agg1;
            S[r][k] = f[(size_t)node * IN_DIM + k] + ag[(size_t)node * IN_DIM + k];
        }
        __syncthreads();

        const int node = v0 + ln;
        float4 acc1 = {0.f, 0.f, 0.f, 0.f};
        float4 acc2 = {0.f, 0.f, 0.f, 0.f};
        const float* s1 = S[ln * 2];
        const float* s2 = S[ln * 2 + 1];
        #pragma unroll 8
        for (int k = 0; k < IN_DIM; k += 4) {
            const float4 sa = *reinterpret_cast<const float4*>(s1 + k);
            const float4 sb = *reinterpret_cast<const float4*>(s2 + k);
            const float4 w0 = *reinterpret_cast<const float4*>(&Wt[k + 0][o4]);
            const float4 w1 = *reinterpret_cast<const float4*>(&Wt[k + 1][o4]);
            const float4 w2 = *reinterpret_cast<const float4*>(&Wt[k + 2][o4]);
            const float4 w3 = *reinterpret_cast<const float4*>(&Wt[k + 3][o4]);
            fma4(acc1, w0, sa.x); fma4(acc1, w1, sa.y); fma4(acc1, w2, sa.z); fma4(acc1, w3, sa.w);
            fma4(acc2, w0, sb.x); fma4(acc2, w1, sb.y); fma4(acc2, w2, sb.z); fma4(acc2, w3, sb.w);
        }
        float4 r;
        r.x = elu_f(a0 * (acc1.x + bias.x)) + elu_f(a1 * (acc2.x + bias.x));
        r.y = elu_f(a0 * (acc1.y + bias.y)) + elu_f(a1 * (acc2.y + bias.y));
        r.z = elu_f(a0 * (acc1.z + bias.z)) + elu_f(a1 * (acc2.z + bias.z));
        r.w = elu_f(a0 * (acc1.w + bias.w)) + elu_f(a1 * (acc2.w + bias.w));
        *reinterpret_cast<float4*>(x1 + (size_t)node * HIDDEN + o4) = r;
    }
}

// ---------------------------------------------------------------------------
// Layer 2: out[v] = elu(a0*((x1[v]+agg1[v])@W2^T + b2)) +
//                   elu(a1*((x1[v]+agg2[v])@W2^T + b2))
// W2 is [64][128]; staged transposed (Wt[k][c]). 16 nodes per tile.
// ---------------------------------------------------------------------------
__global__ __launch_bounds__(256) void k_layer2(
    const float* __restrict__ x1,
    const float* __restrict__ agg1, const float* __restrict__ agg2,
    const float* __restrict__ W2, const float* __restrict__ b2,
    const float* __restrict__ attn, float* __restrict__ out)
{
    __shared__ float Wt[IN_DIM][CLASSES + 4];  // Wt[k][c] = W2[c][k]; row 68 floats (16B aligned)
    __shared__ float S[32][IN_DIM];            // 16 nodes x 2 graphs

    const int t = threadIdx.x;
    for (int i = t; i < CLASSES * IN_DIM; i += 256) {
        const int c = i >> 7, k = i & 127;
        Wt[k][c] = W2[i];
    }
    const float a0 = attn[0], a1 = attn[1];
    const int c4 = (t & 15) * 4;
    const int ln = t >> 4;  // 0..15
    const float4 bias = *reinterpret_cast<const float4*>(b2 + c4);

    const int ntiles = N_NODES / 16;  // 3125, exact
    for (int tile = blockIdx.x; tile < ntiles; tile += gridDim.x) {
        const int v0 = tile * 16;
        __syncthreads();
        // load S: 16 nodes x 2 graphs x 128 = 4096 floats
        for (int i = t; i < 4096; i += 256) {
            const int r = i >> 7, k = i & 127;
            const int node = v0 + (r >> 1);
            const float* ag = (r & 1) ? agg2 : agg1;
            S[r][k] = x1[(size_t)node * IN_DIM + k] + ag[(size_t)node * IN_DIM + k];
        }
        __syncthreads();

        const int node = v0 + ln;
        float4 acc1 = {0.f, 0.f, 0.f, 0.f};
        float4 acc2 = {0.f, 0.f, 0.f, 0.f};
        const float* s1 = S[ln * 2];
        const float* s2 = S[ln * 2 + 1];
        #pragma unroll 8
        for (int k = 0; k < IN_DIM; k += 4) {
            const float4 sa = *reinterpret_cast<const float4*>(s1 + k);
            const float4 sb = *reinterpret_cast<const float4*>(s2 + k);
            const float4 w0 = *reinterpret_cast<const float4*>(&Wt[k + 0][c4]);
            const float4 w1 = *reinterpret_cast<const float4*>(&Wt[k + 1][c4]);
            const float4 w2 = *reinterpret_cast<const float4*>(&Wt[k + 2][c4]);
            const float4 w3 = *reinterpret_cast<const float4*>(&Wt[k + 3][c4]);
            fma4(acc1, w0, sa.x); fma4(acc1, w1, sa.y); fma4(acc1, w2, sa.z); fma4(acc1, w3, sa.w);
            fma4(acc2, w0, sb.x); fma4(acc2, w1, sb.y); fma4(acc2, w2, sb.z); fma4(acc2, w3, sb.w);
        }
        float4 r;
        r.x = elu_f(a0 * (acc1.x + bias.x)) + elu_f(a1 * (acc2.x + bias.x));
        r.y = elu_f(a0 * (acc1.y + bias.y)) + elu_f(a1 * (acc2.y + bias.y));
        r.z = elu_f(a0 * (acc1.z + bias.z)) + elu_f(a1 * (acc2.z + bias.z));
        r.w = elu_f(a0 * (acc1.w + bias.w)) + elu_f(a1 * (acc2.w + bias.w));
        *reinterpret_cast<float4*>(out + (size_t)node * CLASSES + c4) = r;
    }
}

extern "C" void kernel_launch(void* const* d_in, const int* in_sizes, int n_in,
                              void* d_out, int out_size, void* d_ws, size_t ws_size,
                              hipStream_t stream)
{
    const float* features = (const float*)d_in[0];
    const float* W1   = (const float*)d_in[1];
    const float* b1   = (const float*)d_in[2];
    const float* W2   = (const float*)d_in[3];
    const float* b2   = (const float*)d_in[4];
    const float* attn = (const float*)d_in[5];
    const int* src1   = (const int*)d_in[6];
    const int* dst1   = (const int*)d_in[7];
    const int* src2   = (const int*)d_in[8];
    const int* dst2   = (const int*)d_in[9];
    float* out = (float*)d_out;

    const size_t A = (size_t)N_NODES * HIDDEN;  // 6.4M floats
    float* agg1 = (float*)d_ws;
    float* agg2 = agg1 + A;
    float* x1   = agg2 + A;

    // ---- layer 1 ----
    hipMemsetAsync(agg1, 0, 2 * A * sizeof(float), stream);
    k_agg<<<8192, 256, 0, stream>>>(features, src1, dst1, src2, dst2, agg1, agg2);
    k_layer1<<<2048, 256, 0, stream>>>(features, agg1, agg2, W1, b1, attn, x1);

    // ---- layer 2 ----
    hipMemsetAsync(agg1, 0, 2 * A * sizeof(float), stream);
    k_agg<<<8192, 256, 0, stream>>>(x1, src1, dst1, src2, dst2, agg1, agg2);
    k_layer2<<<2048, 256, 0, stream>>>(x1, agg1, agg2, W2, b2, attn, out);
}

// Round 3
// 537.951 us; speedup vs baseline: 5.2773x; 5.2773x over previous
//
#include <hip/hip_runtime.h>
#include <math.h>

#define N_NODES 50000
#define N_EDGES 800000
#define IN_DIM 128
#define HIDDEN 128
#define CLASSES 64

#define N2 100000          // concatenated node space: graph1 [0,50000), graph2 [50000,100000)
#define SCAN_TPB 256
#define SCAN_EPB 1024      // 256 threads * 4 elements
#define SCAN_NBLK 98       // ceil(100000/1024)

static __device__ __forceinline__ float elu_f(float x) {
    return x > 0.f ? x : (expf(x) - 1.f);
}

static __device__ __forceinline__ void fma4(float4& a, const float4 w, const float s) {
    a.x = fmaf(w.x, s, a.x);
    a.y = fmaf(w.y, s, a.y);
    a.z = fmaf(w.z, s, a.z);
    a.w = fmaf(w.w, s, a.w);
}

// ---------------------------------------------------------------------------
// CSR build: histogram -> 3-phase exclusive scan -> bucket fill.
// Both graphs concatenated: node index idx = g*50000 + v. One shared csr
// array (graph2's slots naturally follow graph1's, since scan is over the
// concatenated counts).
// ---------------------------------------------------------------------------
__global__ __launch_bounds__(256) void k_hist(
    const int* __restrict__ dst1, const int* __restrict__ dst2, int* __restrict__ cnt)
{
    int i = blockIdx.x * 256 + threadIdx.x;
    const int stride = gridDim.x * 256;
    for (; i < 2 * N_EDGES; i += stride) {
        const int idx = (i < N_EDGES) ? dst1[i] : (N_NODES + dst2[i - N_EDGES]);
        atomicAdd(&cnt[idx], 1);
    }
}

__global__ __launch_bounds__(SCAN_TPB) void k_scan1(
    const int* __restrict__ cnt, int* __restrict__ off, int* __restrict__ partials)
{
    __shared__ int lds[SCAN_TPB];
    const int b = blockIdx.x, t = threadIdx.x;
    const int base = b * SCAN_EPB + t * 4;
    const int v0 = (base + 0 < N2) ? cnt[base + 0] : 0;
    const int v1 = (base + 1 < N2) ? cnt[base + 1] : 0;
    const int v2 = (base + 2 < N2) ? cnt[base + 2] : 0;
    const int v3 = (base + 3 < N2) ? cnt[base + 3] : 0;
    lds[t] = v0 + v1 + v2 + v3;
    __syncthreads();
    for (int d = 1; d < SCAN_TPB; d <<= 1) {
        const int x = (t >= d) ? lds[t - d] : 0;
        __syncthreads();
        lds[t] += x;
        __syncthreads();
    }
    const int excl = (t == 0) ? 0 : lds[t - 1];
    if (t == SCAN_TPB - 1) partials[b] = lds[t];
    if (base + 0 < N2) off[base + 0] = excl;
    if (base + 1 < N2) off[base + 1] = excl + v0;
    if (base + 2 < N2) off[base + 2] = excl + v0 + v1;
    if (base + 3 < N2) off[base + 3] = excl + v0 + v1 + v2;
}

__global__ __launch_bounds__(128) void k_scan2(int* __restrict__ partials)
{
    __shared__ int lds[128];
    const int t = threadIdx.x;
    lds[t] = (t < SCAN_NBLK) ? partials[t] : 0;
    __syncthreads();
    for (int d = 1; d < 128; d <<= 1) {
        const int x = (t >= d) ? lds[t - d] : 0;
        __syncthreads();
        lds[t] += x;
        __syncthreads();
    }
    if (t < SCAN_NBLK) partials[t] = (t == 0) ? 0 : lds[t - 1];
}

__global__ __launch_bounds__(SCAN_TPB) void k_scan3(
    int* __restrict__ off, const int* __restrict__ partials, int* __restrict__ cur)
{
    const int b = blockIdx.x, t = threadIdx.x;
    const int base = partials[b];
    const int i0 = b * SCAN_EPB + t * 4;
    #pragma unroll
    for (int u = 0; u < 4; ++u) {
        const int i = i0 + u;
        if (i < N2) {
            const int v = off[i] + base;
            off[i] = v;
            cur[i] = v;
        }
    }
    if (b == 0 && t == 0) off[N2] = 2 * N_EDGES;
}

__global__ __launch_bounds__(256) void k_fill(
    const int* __restrict__ src1, const int* __restrict__ dst1,
    const int* __restrict__ src2, const int* __restrict__ dst2,
    int* __restrict__ cur, int* __restrict__ csr)
{
    int i = blockIdx.x * 256 + threadIdx.x;
    const int stride = gridDim.x * 256;
    for (; i < 2 * N_EDGES; i += stride) {
        int s, idx;
        if (i < N_EDGES) { s = src1[i]; idx = dst1[i]; }
        else             { s = src2[i - N_EDGES]; idx = N_NODES + dst2[i - N_EDGES]; }
        const int pos = atomicAdd(&cur[idx], 1);
        csr[pos] = s;
    }
}

// ---------------------------------------------------------------------------
// GEMM 1: y1 = f @ W1^T   (no bias — bias folded into the pull epilogue).
// W1 [128][128] staged transposed in LDS; 16 nodes/tile; thread = 2 nodes x 4 outs.
// ---------------------------------------------------------------------------
__global__ __launch_bounds__(256) void k_gemm1(
    const float* __restrict__ f, const float* __restrict__ W1, float* __restrict__ y1)
{
    __shared__ float Wt[IN_DIM][HIDDEN + 4];
    __shared__ float S[16][IN_DIM];

    const int t = threadIdx.x;
    for (int i = t; i < HIDDEN * IN_DIM; i += 256) {
        const int o = i >> 7, k = i & 127;
        Wt[k][o] = W1[i];
    }
    const int o4 = (t & 31) * 4;
    const int ln = t >> 5;  // 0..7 -> node pair

    const int ntiles = N_NODES / 16;  // 3125 exact
    for (int tile = blockIdx.x; tile < ntiles; tile += gridDim.x) {
        const int v0 = tile * 16;
        __syncthreads();
        for (int i = t; i < 16 * IN_DIM; i += 256) {
            const int r = i >> 7, k = i & 127;
            S[r][k] = f[(size_t)(v0 + r) * IN_DIM + k];
        }
        __syncthreads();

        float4 acc1 = {0.f, 0.f, 0.f, 0.f};
        float4 acc2 = {0.f, 0.f, 0.f, 0.f};
        const float* s1 = S[ln * 2];
        const float* s2 = S[ln * 2 + 1];
        #pragma unroll 8
        for (int k = 0; k < IN_DIM; k += 4) {
            const float4 sa = *reinterpret_cast<const float4*>(s1 + k);
            const float4 sb = *reinterpret_cast<const float4*>(s2 + k);
            const float4 w0 = *reinterpret_cast<const float4*>(&Wt[k + 0][o4]);
            const float4 w1 = *reinterpret_cast<const float4*>(&Wt[k + 1][o4]);
            const float4 w2 = *reinterpret_cast<const float4*>(&Wt[k + 2][o4]);
            const float4 w3 = *reinterpret_cast<const float4*>(&Wt[k + 3][o4]);
            fma4(acc1, w0, sa.x); fma4(acc1, w1, sa.y); fma4(acc1, w2, sa.z); fma4(acc1, w3, sa.w);
            fma4(acc2, w0, sb.x); fma4(acc2, w1, sb.y); fma4(acc2, w2, sb.z); fma4(acc2, w3, sb.w);
        }
        *reinterpret_cast<float4*>(y1 + (size_t)(v0 + ln * 2)     * HIDDEN + o4) = acc1;
        *reinterpret_cast<float4*>(y1 + (size_t)(v0 + ln * 2 + 1) * HIDDEN + o4) = acc2;
    }
}

// ---------------------------------------------------------------------------
// GEMM 2: y2 = x1 @ W2^T   (no bias). W2 [64][128]; 32 nodes/tile.
// ---------------------------------------------------------------------------
__global__ __launch_bounds__(256) void k_gemm2(
    const float* __restrict__ x1, const float* __restrict__ W2, float* __restrict__ y2)
{
    __shared__ float Wt[IN_DIM][CLASSES + 4];
    __shared__ float S[32][IN_DIM];

    const int t = threadIdx.x;
    for (int i = t; i < CLASSES * IN_DIM; i += 256) {
        const int c = i >> 7, k = i & 127;
        Wt[k][c] = W2[i];
    }
    const int c4 = (t & 15) * 4;
    const int ln = t >> 4;  // 0..15 -> node pair

    const int ntiles = (N_NODES + 31) / 32;  // 1563 (last tile partial)
    for (int tile = blockIdx.x; tile < ntiles; tile += gridDim.x) {
        const int v0 = tile * 32;
        __syncthreads();
        for (int i = t; i < 32 * IN_DIM; i += 256) {
            const int r = i >> 7, k = i & 127;
            const int node = v0 + r;
            S[r][k] = (node < N_NODES) ? x1[(size_t)node * IN_DIM + k] : 0.f;
        }
        __syncthreads();

        float4 acc1 = {0.f, 0.f, 0.f, 0.f};
        float4 acc2 = {0.f, 0.f, 0.f, 0.f};
        const float* s1 = S[ln * 2];
        const float* s2 = S[ln * 2 + 1];
        #pragma unroll 8
        for (int k = 0; k < IN_DIM; k += 4) {
            const float4 sa = *reinterpret_cast<const float4*>(s1 + k);
            const float4 sb = *reinterpret_cast<const float4*>(s2 + k);
            const float4 w0 = *reinterpret_cast<const float4*>(&Wt[k + 0][c4]);
            const float4 w1 = *reinterpret_cast<const float4*>(&Wt[k + 1][c4]);
            const float4 w2 = *reinterpret_cast<const float4*>(&Wt[k + 2][c4]);
            const float4 w3 = *reinterpret_cast<const float4*>(&Wt[k + 3][c4]);
            fma4(acc1, w0, sa.x); fma4(acc1, w1, sa.y); fma4(acc1, w2, sa.z); fma4(acc1, w3, sa.w);
            fma4(acc2, w0, sb.x); fma4(acc2, w1, sb.y); fma4(acc2, w2, sb.z); fma4(acc2, w3, sb.w);
        }
        const int na = v0 + ln * 2, nb = na + 1;
        if (na < N_NODES) *reinterpret_cast<float4*>(y2 + (size_t)na * CLASSES + c4) = acc1;
        if (nb < N_NODES) *reinterpret_cast<float4*>(y2 + (size_t)nb * CLASSES + c4) = acc2;
    }
}

// ---------------------------------------------------------------------------
// Fused pull-aggregation + epilogue, layer 1 (dim 128).
// One wave per node; lane holds float2 slice. For both graphs:
//   z_g = sum over in-edges of y1[src];  x1[v] = elu(a0*(y+z1+b)) + elu(a1*(y+z2+b))
// ---------------------------------------------------------------------------
__global__ __launch_bounds__(256) void k_pull1(
    const float* __restrict__ y1, const int* __restrict__ off, const int* __restrict__ csr,
    const float* __restrict__ b1, const float* __restrict__ attn, float* __restrict__ x1)
{
    const int lane = threadIdx.x & 63;
    const int v = (blockIdx.x * 256 + threadIdx.x) >> 6;
    if (v >= N_NODES) return;
    const int c = lane * 2;

    float2 acc1 = {0.f, 0.f}, acc2 = {0.f, 0.f};
    #pragma unroll
    for (int g = 0; g < 2; ++g) {
        const int idx = g * N_NODES + v;
        const int beg = off[idx], end = off[idx + 1];
        float2 acc = {0.f, 0.f};
        int j = beg;
        for (; j + 4 <= end; j += 4) {
            const int s0 = csr[j], s1 = csr[j + 1], s2 = csr[j + 2], s3 = csr[j + 3];
            const float2 r0 = *reinterpret_cast<const float2*>(y1 + (size_t)s0 * HIDDEN + c);
            const float2 r1 = *reinterpret_cast<const float2*>(y1 + (size_t)s1 * HIDDEN + c);
            const float2 r2 = *reinterpret_cast<const float2*>(y1 + (size_t)s2 * HIDDEN + c);
            const float2 r3 = *reinterpret_cast<const float2*>(y1 + (size_t)s3 * HIDDEN + c);
            acc.x += (r0.x + r1.x) + (r2.x + r3.x);
            acc.y += (r0.y + r1.y) + (r2.y + r3.y);
        }
        for (; j < end; ++j) {
            const int s = csr[j];
            const float2 r = *reinterpret_cast<const float2*>(y1 + (size_t)s * HIDDEN + c);
            acc.x += r.x; acc.y += r.y;
        }
        if (g == 0) acc1 = acc; else acc2 = acc;
    }

    const float2 yv = *reinterpret_cast<const float2*>(y1 + (size_t)v * HIDDEN + c);
    const float2 bb = *reinterpret_cast<const float2*>(b1 + c);
    const float a0 = attn[0], a1 = attn[1];
    float2 r;
    r.x = elu_f(a0 * (yv.x + acc1.x + bb.x)) + elu_f(a1 * (yv.x + acc2.x + bb.x));
    r.y = elu_f(a0 * (yv.y + acc1.y + bb.y)) + elu_f(a1 * (yv.y + acc2.y + bb.y));
    *reinterpret_cast<float2*>(x1 + (size_t)v * HIDDEN + c) = r;
}

// ---------------------------------------------------------------------------
// Fused pull-aggregation + epilogue, layer 2 (dim 64). Lane holds 1 float.
// ---------------------------------------------------------------------------
__global__ __launch_bounds__(256) void k_pull2(
    const float* __restrict__ y2, const int* __restrict__ off, const int* __restrict__ csr,
    const float* __restrict__ b2, const float* __restrict__ attn, float* __restrict__ out)
{
    const int lane = threadIdx.x & 63;
    const int v = (blockIdx.x * 256 + threadIdx.x) >> 6;
    if (v >= N_NODES) return;

    float acc1 = 0.f, acc2 = 0.f;
    #pragma unroll
    for (int g = 0; g < 2; ++g) {
        const int idx = g * N_NODES + v;
        const int beg = off[idx], end = off[idx + 1];
        float acc = 0.f;
        int j = beg;
        for (; j + 4 <= end; j += 4) {
            const int s0 = csr[j], s1 = csr[j + 1], s2 = csr[j + 2], s3 = csr[j + 3];
            const float r0 = y2[(size_t)s0 * CLASSES + lane];
            const float r1 = y2[(size_t)s1 * CLASSES + lane];
            const float r2 = y2[(size_t)s2 * CLASSES + lane];
            const float r3 = y2[(size_t)s3 * CLASSES + lane];
            acc += (r0 + r1) + (r2 + r3);
        }
        for (; j < end; ++j) acc += y2[(size_t)csr[j] * CLASSES + lane];
        if (g == 0) acc1 = acc; else acc2 = acc;
    }

    const float yv = y2[(size_t)v * CLASSES + lane];
    const float bb = b2[lane];
    const float a0 = attn[0], a1 = attn[1];
    out[(size_t)v * CLASSES + lane] =
        elu_f(a0 * (yv + acc1 + bb)) + elu_f(a1 * (yv + acc2 + bb));
}

extern "C" void kernel_launch(void* const* d_in, const int* in_sizes, int n_in,
                              void* d_out, int out_size, void* d_ws, size_t ws_size,
                              hipStream_t stream)
{
    const float* features = (const float*)d_in[0];
    const float* W1   = (const float*)d_in[1];
    const float* b1   = (const float*)d_in[2];
    const float* W2   = (const float*)d_in[3];
    const float* b2   = (const float*)d_in[4];
    const float* attn = (const float*)d_in[5];
    const int* src1   = (const int*)d_in[6];
    const int* dst1   = (const int*)d_in[7];
    const int* src2   = (const int*)d_in[8];
    const int* dst2   = (const int*)d_in[9];
    float* out = (float*)d_out;

    // workspace layout (floats first for alignment)
    float* y1 = (float*)d_ws;                       // 50000*128 = 6.4M
    float* x1 = y1 + (size_t)N_NODES * HIDDEN;      // 6.4M
    float* y2 = x1 + (size_t)N_NODES * HIDDEN;      // 50000*64 = 3.2M
    int* off  = (int*)(y2 + (size_t)N_NODES * CLASSES);  // 100001
    int* cur  = off + (N2 + 1);                     // 100000
    int* csr  = cur + N2;                           // 1.6M
    int* partials = csr + 2 * N_EDGES;              // 98

    // ---- CSR build (shared by both layers) ----
    hipMemsetAsync(cur, 0, N2 * sizeof(int), stream);
    k_hist <<<2048, 256, 0, stream>>>(dst1, dst2, cur);
    k_scan1<<<SCAN_NBLK, SCAN_TPB, 0, stream>>>(cur, off, partials);
    k_scan2<<<1, 128, 0, stream>>>(partials);
    k_scan3<<<SCAN_NBLK, SCAN_TPB, 0, stream>>>(off, partials, cur);
    k_fill <<<2048, 256, 0, stream>>>(src1, dst1, src2, dst2, cur, csr);

    // ---- layer 1: y1 = f@W1^T, then fused pull+elu ----
    k_gemm1<<<3125, 256, 0, stream>>>(features, W1, y1);
    k_pull1<<<12500, 256, 0, stream>>>(y1, off, csr, b1, attn, x1);

    // ---- layer 2: y2 = x1@W2^T, then fused pull+elu ----
    k_gemm2<<<1563, 256, 0, stream>>>(x1, W2, y2);
    k_pull2<<<12500, 256, 0, stream>>>(y2, off, csr, b2, attn, out);
}

// Round 6
// 412.811 us; speedup vs baseline: 6.8771x; 1.3031x over previous
//
#include <hip/hip_runtime.h>
#include <math.h>

#define N_NODES 50000
#define N_EDGES 800000
#define IN_DIM 128
#define HIDDEN 128
#define CLASSES 64
#define N2 100000     // concatenated node space: graph1 [0,50000), graph2 [50000,100000)
#define CAP 64        // padded bucket capacity; deg ~ Poisson(16), P(>64) ~ 1e-19

static __device__ __forceinline__ float elu_f(float x) {
    return x > 0.f ? x : (expf(x) - 1.f);
}

static __device__ __forceinline__ void fma4(float4& a, const float4 w, const float s) {
    a.x = fmaf(w.x, s, a.x);
    a.y = fmaf(w.y, s, a.y);
    a.z = fmaf(w.z, s, a.z);
    a.w = fmaf(w.w, s, a.w);
}

// f32 -> bf16 (RNE) pack of two values into one uint (lo = first)
static __device__ __forceinline__ unsigned pack_bf2(float a, float b) {
    unsigned ua = __float_as_uint(a);
    ua = (ua + 0x7FFFu + ((ua >> 16) & 1u)) >> 16;
    unsigned ub = __float_as_uint(b);
    ub = (ub + 0x7FFFu + ((ub >> 16) & 1u)) >> 16;
    return ua | (ub << 16);
}

// unpack two bf16 (packed in uint) -> float2
static __device__ __forceinline__ float2 bf2f2(unsigned u) {
    float2 r;
    r.x = __uint_as_float(u << 16);
    r.y = __uint_as_float(u & 0xFFFF0000u);
    return r;
}

// ---------------------------------------------------------------------------
// Fused CSR build: padded per-node buckets. One pass, no scan, no histogram.
// cnt must be zeroed. slots[idx*CAP + r] = src for r-th in-edge of node idx.
// ---------------------------------------------------------------------------
__global__ __launch_bounds__(256) void k_fill_fused(
    const int* __restrict__ src1, const int* __restrict__ dst1,
    const int* __restrict__ src2, const int* __restrict__ dst2,
    int* __restrict__ cnt, int* __restrict__ slots)
{
    const int i = blockIdx.x * 256 + threadIdx.x;
    if (i >= 2 * N_EDGES) return;
    int s, idx;
    if (i < N_EDGES) { s = src1[i]; idx = dst1[i]; }
    else             { s = src2[i - N_EDGES]; idx = N_NODES + dst2[i - N_EDGES]; }
    const int r = atomicAdd(&cnt[idx], 1);
    if (r < CAP) slots[(size_t)idx * CAP + r] = s;
}

// ---------------------------------------------------------------------------
// GEMM 1: y1b = bf16( f @ W1^T )  (bias folded into pull epilogue)
// ---------------------------------------------------------------------------
__global__ __launch_bounds__(256) void k_gemm1(
    const float* __restrict__ f, const float* __restrict__ W1,
    unsigned short* __restrict__ y1b)
{
    __shared__ float Wt[IN_DIM][HIDDEN + 4];
    __shared__ float S[16][IN_DIM];

    const int t = threadIdx.x;
    for (int i = t; i < HIDDEN * IN_DIM; i += 256) {
        const int o = i >> 7, k = i & 127;
        Wt[k][o] = W1[i];
    }
    const int o4 = (t & 31) * 4;
    const int ln = t >> 5;

    const int ntiles = N_NODES / 16;  // 3125 exact
    for (int tile = blockIdx.x; tile < ntiles; tile += gridDim.x) {
        const int v0 = tile * 16;
        __syncthreads();
        for (int i = t; i < 16 * IN_DIM; i += 256) {
            const int r = i >> 7, k = i & 127;
            S[r][k] = f[(size_t)(v0 + r) * IN_DIM + k];
        }
        __syncthreads();

        float4 acc1 = {0.f, 0.f, 0.f, 0.f};
        float4 acc2 = {0.f, 0.f, 0.f, 0.f};
        const float* s1 = S[ln * 2];
        const float* s2 = S[ln * 2 + 1];
        #pragma unroll 8
        for (int k = 0; k < IN_DIM; k += 4) {
            const float4 sa = *reinterpret_cast<const float4*>(s1 + k);
            const float4 sb = *reinterpret_cast<const float4*>(s2 + k);
            const float4 w0 = *reinterpret_cast<const float4*>(&Wt[k + 0][o4]);
            const float4 w1 = *reinterpret_cast<const float4*>(&Wt[k + 1][o4]);
            const float4 w2 = *reinterpret_cast<const float4*>(&Wt[k + 2][o4]);
            const float4 w3 = *reinterpret_cast<const float4*>(&Wt[k + 3][o4]);
            fma4(acc1, w0, sa.x); fma4(acc1, w1, sa.y); fma4(acc1, w2, sa.z); fma4(acc1, w3, sa.w);
            fma4(acc2, w0, sb.x); fma4(acc2, w1, sb.y); fma4(acc2, w2, sb.z); fma4(acc2, w3, sb.w);
        }
        const int na = v0 + ln * 2, nb = na + 1;
        uint2 pa, pb;
        pa.x = pack_bf2(acc1.x, acc1.y); pa.y = pack_bf2(acc1.z, acc1.w);
        pb.x = pack_bf2(acc2.x, acc2.y); pb.y = pack_bf2(acc2.z, acc2.w);
        *reinterpret_cast<uint2*>(y1b + (size_t)na * HIDDEN + o4) = pa;
        *reinterpret_cast<uint2*>(y1b + (size_t)nb * HIDDEN + o4) = pb;
    }
}

// ---------------------------------------------------------------------------
// GEMM 2: y2b = bf16( x1 @ W2^T )
// ---------------------------------------------------------------------------
__global__ __launch_bounds__(256) void k_gemm2(
    const float* __restrict__ x1, const float* __restrict__ W2,
    unsigned short* __restrict__ y2b)
{
    __shared__ float Wt[IN_DIM][CLASSES + 4];
    __shared__ float S[32][IN_DIM];

    const int t = threadIdx.x;
    for (int i = t; i < CLASSES * IN_DIM; i += 256) {
        const int c = i >> 7, k = i & 127;
        Wt[k][c] = W2[i];
    }
    const int c4 = (t & 15) * 4;
    const int ln = t >> 4;

    const int ntiles = (N_NODES + 31) / 32;  // 1563
    for (int tile = blockIdx.x; tile < ntiles; tile += gridDim.x) {
        const int v0 = tile * 32;
        __syncthreads();
        for (int i = t; i < 32 * IN_DIM; i += 256) {
            const int r = i >> 7, k = i & 127;
            const int node = v0 + r;
            S[r][k] = (node < N_NODES) ? x1[(size_t)node * IN_DIM + k] : 0.f;
        }
        __syncthreads();

        float4 acc1 = {0.f, 0.f, 0.f, 0.f};
        float4 acc2 = {0.f, 0.f, 0.f, 0.f};
        const float* s1 = S[ln * 2];
        const float* s2 = S[ln * 2 + 1];
        #pragma unroll 8
        for (int k = 0; k < IN_DIM; k += 4) {
            const float4 sa = *reinterpret_cast<const float4*>(s1 + k);
            const float4 sb = *reinterpret_cast<const float4*>(s2 + k);
            const float4 w0 = *reinterpret_cast<const float4*>(&Wt[k + 0][c4]);
            const float4 w1 = *reinterpret_cast<const float4*>(&Wt[k + 1][c4]);
            const float4 w2 = *reinterpret_cast<const float4*>(&Wt[k + 2][c4]);
            const float4 w3 = *reinterpret_cast<const float4*>(&Wt[k + 3][c4]);
            fma4(acc1, w0, sa.x); fma4(acc1, w1, sa.y); fma4(acc1, w2, sa.z); fma4(acc1, w3, sa.w);
            fma4(acc2, w0, sb.x); fma4(acc2, w1, sb.y); fma4(acc2, w2, sb.z); fma4(acc2, w3, sb.w);
        }
        const int na = v0 + ln * 2, nb = na + 1;
        uint2 pa, pb;
        pa.x = pack_bf2(acc1.x, acc1.y); pa.y = pack_bf2(acc1.z, acc1.w);
        pb.x = pack_bf2(acc2.x, acc2.y); pb.y = pack_bf2(acc2.z, acc2.w);
        if (na < N_NODES) *reinterpret_cast<uint2*>(y2b + (size_t)na * CLASSES + c4) = pa;
        if (nb < N_NODES) *reinterpret_cast<uint2*>(y2b + (size_t)nb * CLASSES + c4) = pb;
    }
}

// ---------------------------------------------------------------------------
// Pull layer 1 (dim 128): one wave per node, lane holds 2 dims (uint = 2 bf16).
// x1[v] = elu(a0*(y[v]+agg1+b1)) + elu(a1*(y[v]+agg2+b1))
// ---------------------------------------------------------------------------
__global__ __launch_bounds__(256) void k_pull1(
    const unsigned short* __restrict__ y1b,
    const int* __restrict__ cnt, const int* __restrict__ slots,
    const float* __restrict__ b1, const float* __restrict__ attn,
    float* __restrict__ x1)
{
    const int lane = threadIdx.x & 63;
    const int v = (blockIdx.x * 256 + threadIdx.x) >> 6;
    if (v >= N_NODES) return;
    const int c = lane * 2;

    float2 acc1 = {0.f, 0.f}, acc2 = {0.f, 0.f};
    #pragma unroll
    for (int g = 0; g < 2; ++g) {
        const int idx = g * N_NODES + v;
        const size_t base = (size_t)idx * CAP;
        const int deg = cnt[idx];
        float2 acc = {0.f, 0.f};
        int j = 0;
        for (; j + 4 <= deg; j += 4) {
            const int s0 = slots[base + j], s1 = slots[base + j + 1];
            const int s2 = slots[base + j + 2], s3 = slots[base + j + 3];
            const float2 r0 = bf2f2(*reinterpret_cast<const unsigned*>(y1b + (size_t)s0 * HIDDEN + c));
            const float2 r1 = bf2f2(*reinterpret_cast<const unsigned*>(y1b + (size_t)s1 * HIDDEN + c));
            const float2 r2 = bf2f2(*reinterpret_cast<const unsigned*>(y1b + (size_t)s2 * HIDDEN + c));
            const float2 r3 = bf2f2(*reinterpret_cast<const unsigned*>(y1b + (size_t)s3 * HIDDEN + c));
            acc.x += (r0.x + r1.x) + (r2.x + r3.x);
            acc.y += (r0.y + r1.y) + (r2.y + r3.y);
        }
        for (; j < deg; ++j) {
            const int s = slots[base + j];
            const float2 r = bf2f2(*reinterpret_cast<const unsigned*>(y1b + (size_t)s * HIDDEN + c));
            acc.x += r.x; acc.y += r.y;
        }
        if (g == 0) acc1 = acc; else acc2 = acc;
    }

    const float2 yv = bf2f2(*reinterpret_cast<const unsigned*>(y1b + (size_t)v * HIDDEN + c));
    const float2 bb = *reinterpret_cast<const float2*>(b1 + c);
    const float a0 = attn[0], a1 = attn[1];
    float2 r;
    r.x = elu_f(a0 * (yv.x + acc1.x + bb.x)) + elu_f(a1 * (yv.x + acc2.x + bb.x));
    r.y = elu_f(a0 * (yv.y + acc1.y + bb.y)) + elu_f(a1 * (yv.y + acc2.y + bb.y));
    *reinterpret_cast<float2*>(x1 + (size_t)v * HIDDEN + c) = r;
}

// ---------------------------------------------------------------------------
// Pull layer 2 (dim 64): one wave per node; half-wave per graph.
// Lanes 0..31 gather graph1, lanes 32..63 gather graph2 (same node), then
// halves exchange via shfl and lanes 0..31 write the combined result.
// ---------------------------------------------------------------------------
__global__ __launch_bounds__(256) void k_pull2(
    const unsigned short* __restrict__ y2b,
    const int* __restrict__ cnt, const int* __restrict__ slots,
    const float* __restrict__ b2, const float* __restrict__ attn,
    float* __restrict__ out)
{
    const int lane = threadIdx.x & 63;
    const int v = (blockIdx.x * 256 + threadIdx.x) >> 6;
    if (v >= N_NODES) return;
    const int half = lane >> 5;       // which graph
    const int l = lane & 31;          // dim pair: dims (2l, 2l+1)
    const int c = l * 2;

    const int idx = half * N_NODES + v;
    const size_t base = (size_t)idx * CAP;
    const int deg = cnt[idx];
    float2 acc = {0.f, 0.f};
    int j = 0;
    for (; j + 4 <= deg; j += 4) {
        const int s0 = slots[base + j], s1 = slots[base + j + 1];
        const int s2 = slots[base + j + 2], s3 = slots[base + j + 3];
        const float2 r0 = bf2f2(*reinterpret_cast<const unsigned*>(y2b + (size_t)s0 * CLASSES + c));
        const float2 r1 = bf2f2(*reinterpret_cast<const unsigned*>(y2b + (size_t)s1 * CLASSES + c));
        const float2 r2 = bf2f2(*reinterpret_cast<const unsigned*>(y2b + (size_t)s2 * CLASSES + c));
        const float2 r3 = bf2f2(*reinterpret_cast<const unsigned*>(y2b + (size_t)s3 * CLASSES + c));
        acc.x += (r0.x + r1.x) + (r2.x + r3.x);
        acc.y += (r0.y + r1.y) + (r2.y + r3.y);
    }
    for (; j < deg; ++j) {
        const int s = slots[base + j];
        const float2 r = bf2f2(*reinterpret_cast<const unsigned*>(y2b + (size_t)s * CLASSES + c));
        acc.x += r.x; acc.y += r.y;
    }

    // exchange halves: lane ^ 32 holds the other graph's acc for same dims
    float2 other;
    other.x = __shfl(acc.x, lane ^ 32);
    other.y = __shfl(acc.y, lane ^ 32);
    const float2 g1 = (half == 0) ? acc : other;
    const float2 g2 = (half == 0) ? other : acc;

    const float2 yv = bf2f2(*reinterpret_cast<const unsigned*>(y2b + (size_t)v * CLASSES + c));
    const float2 bb = *reinterpret_cast<const float2*>(b2 + c);
    const float a0 = attn[0], a1 = attn[1];
    float2 r;
    r.x = elu_f(a0 * (yv.x + g1.x + bb.x)) + elu_f(a1 * (yv.x + g2.x + bb.x));
    r.y = elu_f(a0 * (yv.y + g1.y + bb.y)) + elu_f(a1 * (yv.y + g2.y + bb.y));
    if (half == 0)
        *reinterpret_cast<float2*>(out + (size_t)v * CLASSES + c) = r;
}

extern "C" void kernel_launch(void* const* d_in, const int* in_sizes, int n_in,
                              void* d_out, int out_size, void* d_ws, size_t ws_size,
                              hipStream_t stream)
{
    const float* features = (const float*)d_in[0];
    const float* W1   = (const float*)d_in[1];
    const float* b1   = (const float*)d_in[2];
    const float* W2   = (const float*)d_in[3];
    const float* b2   = (const float*)d_in[4];
    const float* attn = (const float*)d_in[5];
    const int* src1   = (const int*)d_in[6];
    const int* dst1   = (const int*)d_in[7];
    const int* src2   = (const int*)d_in[8];
    const int* dst2   = (const int*)d_in[9];
    float* out = (float*)d_out;

    // workspace layout (all segment sizes multiples of 16 B)
    float* x1 = (float*)d_ws;                                   // 6.4M f32 = 25.6 MB
    unsigned short* y1b = (unsigned short*)(x1 + (size_t)N_NODES * HIDDEN);   // 6.4M bf16 = 12.8 MB
    unsigned short* y2b = y1b + (size_t)N_NODES * HIDDEN;       // 3.2M bf16 = 6.4 MB
    int* cnt  = (int*)(y2b + (size_t)N_NODES * CLASSES);        // 100000 int
    int* slots = cnt + N2;                                      // 6.4M int = 25.6 MB

    // ---- fused CSR build (padded buckets; shared by both layers) ----
    hipMemsetAsync(cnt, 0, N2 * sizeof(int), stream);
    k_fill_fused<<<(2 * N_EDGES + 255) / 256, 256, 0, stream>>>(
        src1, dst1, src2, dst2, cnt, slots);

    // ---- layer 1 ----
    k_gemm1<<<3125, 256, 0, stream>>>(features, W1, y1b);
    k_pull1<<<12500, 256, 0, stream>>>(y1b, cnt, slots, b1, attn, x1);

    // ---- layer 2 ----
    k_gemm2<<<1563, 256, 0, stream>>>(x1, W2, y2b);
    k_pull2<<<12500, 256, 0, stream>>>(y2b, cnt, slots, b2, attn, out);
}

// Round 7
// 325.058 us; speedup vs baseline: 8.7336x; 1.2700x over previous
//
#include <hip/hip_runtime.h>
#include <math.h>

#define N_NODES 50000
#define N_EDGES 800000
#define IN_DIM 128
#define HIDDEN 128
#define CLASSES 64
#define N2 100000      // concatenated node space: graph1 [0,50000), graph2 [50000,100000)

#define BIN_SHIFT 9    // 512 nodes per bin
#define NB 196         // ceil(100000/512)
#define NBLK 192       // edge-partition blocks for P1/P2
#define CHUNK ((2 * N_EDGES + NBLK - 1) / NBLK)

static __device__ __forceinline__ float elu_f(float x) {
    return x > 0.f ? x : (expf(x) - 1.f);
}

static __device__ __forceinline__ void fma4(float4& a, const float4 w, const float s) {
    a.x = fmaf(w.x, s, a.x);
    a.y = fmaf(w.y, s, a.y);
    a.z = fmaf(w.z, s, a.z);
    a.w = fmaf(w.w, s, a.w);
}

// f32 -> bf16 (RNE) pack of two values into one uint (lo = first)
static __device__ __forceinline__ unsigned pack_bf2(float a, float b) {
    unsigned ua = __float_as_uint(a);
    ua = (ua + 0x7FFFu + ((ua >> 16) & 1u)) >> 16;
    unsigned ub = __float_as_uint(b);
    ub = (ub + 0x7FFFu + ((ub >> 16) & 1u)) >> 16;
    return ua | (ub << 16);
}

// unpack two bf16 (packed in uint) -> float2
static __device__ __forceinline__ float2 bf2f2(unsigned u) {
    float2 r;
    r.x = __uint_as_float(u << 16);
    r.y = __uint_as_float(u & 0xFFFF0000u);
    return r;
}

// ---------------------------------------------------------------------------
// P1: per-block LDS histogram over bins. counts[blk*NB + bin].
// ---------------------------------------------------------------------------
__global__ __launch_bounds__(1024) void k_p1_count(
    const int* __restrict__ dst1, const int* __restrict__ dst2,
    int* __restrict__ counts)
{
    __shared__ int hist[NB];
    const int t = threadIdx.x, b = blockIdx.x;
    if (t < NB) hist[t] = 0;
    __syncthreads();
    const int beg = b * CHUNK;
    const int end = min(beg + CHUNK, 2 * N_EDGES);
    for (int i = beg + t; i < end; i += 1024) {
        const int idx = (i < N_EDGES) ? dst1[i] : (N_NODES + dst2[i - N_EDGES]);
        atomicAdd(&hist[idx >> BIN_SHIFT], 1);
    }
    __syncthreads();
    if (t < NB) counts[b * NB + t] = hist[t];
}

// ---------------------------------------------------------------------------
// Scan: binStart[bin] (exclusive over bin totals) and in-place rewrite of
// counts -> per-(blk,bin) start cursors. One block.
// ---------------------------------------------------------------------------
__global__ __launch_bounds__(256) void k_scan_bins(
    int* __restrict__ counts, int* __restrict__ binStart, int* __restrict__ off)
{
    __shared__ int tot[256];
    const int t = threadIdx.x;
    int total = 0;
    if (t < NB) {
        #pragma unroll 8
        for (int blk = 0; blk < NBLK; ++blk) total += counts[blk * NB + t];
    }
    tot[t] = (t < NB) ? total : 0;
    __syncthreads();
    const int v = tot[t];
    for (int d = 1; d < 256; d <<= 1) {
        const int x = (t >= d) ? tot[t - d] : 0;
        __syncthreads();
        tot[t] += x;
        __syncthreads();
    }
    const int excl = tot[t] - v;
    if (t < NB) binStart[t] = excl;
    if (t == NB - 1) binStart[NB] = tot[t];      // == 2*N_EDGES
    if (t == 0) off[N2] = 2 * N_EDGES;           // CSR sentinel
    if (t < NB) {
        int run = excl;
        #pragma unroll 8
        for (int blk = 0; blk < NBLK; ++blk) {
            const int c = counts[blk * NB + t];
            counts[blk * NB + t] = run;
            run += c;
        }
    }
}

// ---------------------------------------------------------------------------
// P2: scatter packed records into per-(blk,bin) contiguous sub-ranges.
// rec = (src << 9) | localDst   (src < 2^16, localDst < 512)
// ---------------------------------------------------------------------------
__global__ __launch_bounds__(1024) void k_p2_scatter(
    const int* __restrict__ src1, const int* __restrict__ dst1,
    const int* __restrict__ src2, const int* __restrict__ dst2,
    const int* __restrict__ counts, unsigned* __restrict__ binned)
{
    __shared__ int cur[NB];
    const int t = threadIdx.x, b = blockIdx.x;
    if (t < NB) cur[t] = counts[b * NB + t];
    __syncthreads();
    const int beg = b * CHUNK;
    const int end = min(beg + CHUNK, 2 * N_EDGES);
    for (int i = beg + t; i < end; i += 1024) {
        int s, idx;
        if (i < N_EDGES) { s = src1[i]; idx = dst1[i]; }
        else             { s = src2[i - N_EDGES]; idx = N_NODES + dst2[i - N_EDGES]; }
        const int bin = idx >> BIN_SHIFT;
        const unsigned rec = ((unsigned)s << BIN_SHIFT) | (unsigned)(idx & 511);
        const int pos = atomicAdd(&cur[bin], 1);
        binned[pos] = rec;
    }
}

// ---------------------------------------------------------------------------
// P3: per-bin CSR build. LDS hist(512) + scan -> off; scatter srcs into the
// bin's contiguous csr window (XCD-local, lines revisited ~deg times).
// ---------------------------------------------------------------------------
__global__ __launch_bounds__(1024) void k_p3_csr(
    const unsigned* __restrict__ binned, const int* __restrict__ binStart,
    int* __restrict__ off, int* __restrict__ csr)
{
    __shared__ int hist[512], sc[512], cur[512];
    const int t = threadIdx.x, bin = blockIdx.x;
    const int bs = binStart[bin], be = binStart[bin + 1];
    const int base = bin << BIN_SHIFT;
    const int nloc = min(512, N2 - base);
    if (t < 512) hist[t] = 0;
    __syncthreads();
    for (int p = bs + t; p < be; p += 1024)
        atomicAdd(&hist[binned[p] & 511u], 1);
    __syncthreads();
    int v = 0;
    if (t < 512) { v = hist[t]; sc[t] = v; }
    __syncthreads();
    for (int d = 1; d < 512; d <<= 1) {
        int x = 0;
        if (t < 512 && t >= d) x = sc[t - d];
        __syncthreads();
        if (t < 512) sc[t] += x;
        __syncthreads();
    }
    if (t < 512) {
        const int excl = sc[t] - v;
        cur[t] = bs + excl;
        if (t < nloc) off[base + t] = bs + excl;
    }
    __syncthreads();
    for (int p = bs + t; p < be; p += 1024) {
        const unsigned rec = binned[p];
        const int pos = atomicAdd(&cur[rec & 511u], 1);
        csr[pos] = (int)(rec >> BIN_SHIFT);
    }
}

// ---------------------------------------------------------------------------
// GEMM 1: y1b = bf16( f @ W1^T )  (bias folded into pull epilogue)
// ---------------------------------------------------------------------------
__global__ __launch_bounds__(256) void k_gemm1(
    const float* __restrict__ f, const float* __restrict__ W1,
    unsigned short* __restrict__ y1b)
{
    __shared__ float Wt[IN_DIM][HIDDEN + 4];
    __shared__ float S[16][IN_DIM];

    const int t = threadIdx.x;
    for (int i = t; i < HIDDEN * IN_DIM; i += 256) {
        const int o = i >> 7, k = i & 127;
        Wt[k][o] = W1[i];
    }
    const int o4 = (t & 31) * 4;
    const int ln = t >> 5;

    const int ntiles = N_NODES / 16;  // 3125 exact
    for (int tile = blockIdx.x; tile < ntiles; tile += gridDim.x) {
        const int v0 = tile * 16;
        __syncthreads();
        for (int i = t; i < 16 * IN_DIM; i += 256) {
            const int r = i >> 7, k = i & 127;
            S[r][k] = f[(size_t)(v0 + r) * IN_DIM + k];
        }
        __syncthreads();

        float4 acc1 = {0.f, 0.f, 0.f, 0.f};
        float4 acc2 = {0.f, 0.f, 0.f, 0.f};
        const float* s1 = S[ln * 2];
        const float* s2 = S[ln * 2 + 1];
        #pragma unroll 8
        for (int k = 0; k < IN_DIM; k += 4) {
            const float4 sa = *reinterpret_cast<const float4*>(s1 + k);
            const float4 sb = *reinterpret_cast<const float4*>(s2 + k);
            const float4 w0 = *reinterpret_cast<const float4*>(&Wt[k + 0][o4]);
            const float4 w1 = *reinterpret_cast<const float4*>(&Wt[k + 1][o4]);
            const float4 w2 = *reinterpret_cast<const float4*>(&Wt[k + 2][o4]);
            const float4 w3 = *reinterpret_cast<const float4*>(&Wt[k + 3][o4]);
            fma4(acc1, w0, sa.x); fma4(acc1, w1, sa.y); fma4(acc1, w2, sa.z); fma4(acc1, w3, sa.w);
            fma4(acc2, w0, sb.x); fma4(acc2, w1, sb.y); fma4(acc2, w2, sb.z); fma4(acc2, w3, sb.w);
        }
        const int na = v0 + ln * 2, nb = na + 1;
        uint2 pa, pb;
        pa.x = pack_bf2(acc1.x, acc1.y); pa.y = pack_bf2(acc1.z, acc1.w);
        pb.x = pack_bf2(acc2.x, acc2.y); pb.y = pack_bf2(acc2.z, acc2.w);
        *reinterpret_cast<uint2*>(y1b + (size_t)na * HIDDEN + o4) = pa;
        *reinterpret_cast<uint2*>(y1b + (size_t)nb * HIDDEN + o4) = pb;
    }
}

// ---------------------------------------------------------------------------
// GEMM 2: y2b = bf16( x1 @ W2^T )
// ---------------------------------------------------------------------------
__global__ __launch_bounds__(256) void k_gemm2(
    const float* __restrict__ x1, const float* __restrict__ W2,
    unsigned short* __restrict__ y2b)
{
    __shared__ float Wt[IN_DIM][CLASSES + 4];
    __shared__ float S[32][IN_DIM];

    const int t = threadIdx.x;
    for (int i = t; i < CLASSES * IN_DIM; i += 256) {
        const int c = i >> 7, k = i & 127;
        Wt[k][c] = W2[i];
    }
    const int c4 = (t & 15) * 4;
    const int ln = t >> 4;

    const int ntiles = (N_NODES + 31) / 32;  // 1563
    for (int tile = blockIdx.x; tile < ntiles; tile += gridDim.x) {
        const int v0 = tile * 32;
        __syncthreads();
        for (int i = t; i < 32 * IN_DIM; i += 256) {
            const int r = i >> 7, k = i & 127;
            const int node = v0 + r;
            S[r][k] = (node < N_NODES) ? x1[(size_t)node * IN_DIM + k] : 0.f;
        }
        __syncthreads();

        float4 acc1 = {0.f, 0.f, 0.f, 0.f};
        float4 acc2 = {0.f, 0.f, 0.f, 0.f};
        const float* s1 = S[ln * 2];
        const float* s2 = S[ln * 2 + 1];
        #pragma unroll 8
        for (int k = 0; k < IN_DIM; k += 4) {
            const float4 sa = *reinterpret_cast<const float4*>(s1 + k);
            const float4 sb = *reinterpret_cast<const float4*>(s2 + k);
            const float4 w0 = *reinterpret_cast<const float4*>(&Wt[k + 0][c4]);
            const float4 w1 = *reinterpret_cast<const float4*>(&Wt[k + 1][c4]);
            const float4 w2 = *reinterpret_cast<const float4*>(&Wt[k + 2][c4]);
            const float4 w3 = *reinterpret_cast<const float4*>(&Wt[k + 3][c4]);
            fma4(acc1, w0, sa.x); fma4(acc1, w1, sa.y); fma4(acc1, w2, sa.z); fma4(acc1, w3, sa.w);
            fma4(acc2, w0, sb.x); fma4(acc2, w1, sb.y); fma4(acc2, w2, sb.z); fma4(acc2, w3, sb.w);
        }
        const int na = v0 + ln * 2, nb = na + 1;
        uint2 pa, pb;
        pa.x = pack_bf2(acc1.x, acc1.y); pa.y = pack_bf2(acc1.z, acc1.w);
        pb.x = pack_bf2(acc2.x, acc2.y); pb.y = pack_bf2(acc2.z, acc2.w);
        if (na < N_NODES) *reinterpret_cast<uint2*>(y2b + (size_t)na * CLASSES + c4) = pa;
        if (nb < N_NODES) *reinterpret_cast<uint2*>(y2b + (size_t)nb * CLASSES + c4) = pb;
    }
}

// ---------------------------------------------------------------------------
// Pull layer 1 (dim 128): one wave per node, lane holds 2 dims (uint = 2 bf16).
// ---------------------------------------------------------------------------
__global__ __launch_bounds__(256) void k_pull1(
    const unsigned short* __restrict__ y1b,
    const int* __restrict__ off, const int* __restrict__ csr,
    const float* __restrict__ b1, const float* __restrict__ attn,
    float* __restrict__ x1)
{
    const int lane = threadIdx.x & 63;
    const int v = (blockIdx.x * 256 + threadIdx.x) >> 6;
    if (v >= N_NODES) return;
    const int c = lane * 2;

    float2 acc1 = {0.f, 0.f}, acc2 = {0.f, 0.f};
    #pragma unroll
    for (int g = 0; g < 2; ++g) {
        const int idx = g * N_NODES + v;
        const int beg = off[idx], end_ = off[idx + 1];
        float2 acc = {0.f, 0.f};
        int j = beg;
        for (; j + 4 <= end_; j += 4) {
            const int s0 = csr[j], s1 = csr[j + 1], s2 = csr[j + 2], s3 = csr[j + 3];
            const float2 r0 = bf2f2(*reinterpret_cast<const unsigned*>(y1b + (size_t)s0 * HIDDEN + c));
            const float2 r1 = bf2f2(*reinterpret_cast<const unsigned*>(y1b + (size_t)s1 * HIDDEN + c));
            const float2 r2 = bf2f2(*reinterpret_cast<const unsigned*>(y1b + (size_t)s2 * HIDDEN + c));
            const float2 r3 = bf2f2(*reinterpret_cast<const unsigned*>(y1b + (size_t)s3 * HIDDEN + c));
            acc.x += (r0.x + r1.x) + (r2.x + r3.x);
            acc.y += (r0.y + r1.y) + (r2.y + r3.y);
        }
        for (; j < end_; ++j) {
            const int s = csr[j];
            const float2 r = bf2f2(*reinterpret_cast<const unsigned*>(y1b + (size_t)s * HIDDEN + c));
            acc.x += r.x; acc.y += r.y;
        }
        if (g == 0) acc1 = acc; else acc2 = acc;
    }

    const float2 yv = bf2f2(*reinterpret_cast<const unsigned*>(y1b + (size_t)v * HIDDEN + c));
    const float2 bb = *reinterpret_cast<const float2*>(b1 + c);
    const float a0 = attn[0], a1 = attn[1];
    float2 r;
    r.x = elu_f(a0 * (yv.x + acc1.x + bb.x)) + elu_f(a1 * (yv.x + acc2.x + bb.x));
    r.y = elu_f(a0 * (yv.y + acc1.y + bb.y)) + elu_f(a1 * (yv.y + acc2.y + bb.y));
    *reinterpret_cast<float2*>(x1 + (size_t)v * HIDDEN + c) = r;
}

// ---------------------------------------------------------------------------
// Pull layer 2 (dim 64): one wave per node; half-wave per graph; shfl merge.
// ---------------------------------------------------------------------------
__global__ __launch_bounds__(256) void k_pull2(
    const unsigned short* __restrict__ y2b,
    const int* __restrict__ off, const int* __restrict__ csr,
    const float* __restrict__ b2, const float* __restrict__ attn,
    float* __restrict__ out)
{
    const int lane = threadIdx.x & 63;
    const int v = (blockIdx.x * 256 + threadIdx.x) >> 6;
    if (v >= N_NODES) return;
    const int half = lane >> 5;
    const int l = lane & 31;
    const int c = l * 2;

    const int idx = half * N_NODES + v;
    const int beg = off[idx], end_ = off[idx + 1];
    float2 acc = {0.f, 0.f};
    int j = beg;
    for (; j + 4 <= end_; j += 4) {
        const int s0 = csr[j], s1 = csr[j + 1], s2 = csr[j + 2], s3 = csr[j + 3];
        const float2 r0 = bf2f2(*reinterpret_cast<const unsigned*>(y2b + (size_t)s0 * CLASSES + c));
        const float2 r1 = bf2f2(*reinterpret_cast<const unsigned*>(y2b + (size_t)s1 * CLASSES + c));
        const float2 r2 = bf2f2(*reinterpret_cast<const unsigned*>(y2b + (size_t)s2 * CLASSES + c));
        const float2 r3 = bf2f2(*reinterpret_cast<const unsigned*>(y2b + (size_t)s3 * CLASSES + c));
        acc.x += (r0.x + r1.x) + (r2.x + r3.x);
        acc.y += (r0.y + r1.y) + (r2.y + r3.y);
    }
    for (; j < end_; ++j) {
        const int s = csr[j];
        const float2 r = bf2f2(*reinterpret_cast<const unsigned*>(y2b + (size_t)s * CLASSES + c));
        acc.x += r.x; acc.y += r.y;
    }

    float2 other;
    other.x = __shfl(acc.x, lane ^ 32);
    other.y = __shfl(acc.y, lane ^ 32);
    const float2 g1 = (half == 0) ? acc : other;
    const float2 g2 = (half == 0) ? other : acc;

    const float2 yv = bf2f2(*reinterpret_cast<const unsigned*>(y2b + (size_t)v * CLASSES + c));
    const float2 bb = *reinterpret_cast<const float2*>(b2 + c);
    const float a0 = attn[0], a1 = attn[1];
    float2 r;
    r.x = elu_f(a0 * (yv.x + g1.x + bb.x)) + elu_f(a1 * (yv.x + g2.x + bb.x));
    r.y = elu_f(a0 * (yv.y + g1.y + bb.y)) + elu_f(a1 * (yv.y + g2.y + bb.y));
    if (half == 0)
        *reinterpret_cast<float2*>(out + (size_t)v * CLASSES + c) = r;
}

extern "C" void kernel_launch(void* const* d_in, const int* in_sizes, int n_in,
                              void* d_out, int out_size, void* d_ws, size_t ws_size,
                              hipStream_t stream)
{
    const float* features = (const float*)d_in[0];
    const float* W1   = (const float*)d_in[1];
    const float* b1   = (const float*)d_in[2];
    const float* W2   = (const float*)d_in[3];
    const float* b2   = (const float*)d_in[4];
    const float* attn = (const float*)d_in[5];
    const int* src1   = (const int*)d_in[6];
    const int* dst1   = (const int*)d_in[7];
    const int* src2   = (const int*)d_in[8];
    const int* dst2   = (const int*)d_in[9];
    float* out = (float*)d_out;

    // workspace layout
    float* x1 = (float*)d_ws;                                        // 6.4M f32
    unsigned short* y1b = (unsigned short*)(x1 + (size_t)N_NODES * HIDDEN);   // 6.4M bf16
    unsigned short* y2b = y1b + (size_t)N_NODES * HIDDEN;            // 3.2M bf16
    int* off      = (int*)(y2b + (size_t)N_NODES * CLASSES);         // N2+1
    int* binStart = off + (N2 + 1);                                  // NB+1
    int* counts   = binStart + (NB + 1);                             // NBLK*NB
    unsigned* binned = (unsigned*)(counts + NBLK * NB);              // 1.6M
    int* csr      = (int*)(binned + 2 * N_EDGES);                    // 1.6M

    // ---- binned CSR build (shared by both layers) ----
    k_p1_count  <<<NBLK, 1024, 0, stream>>>(dst1, dst2, counts);
    k_scan_bins <<<1, 256, 0, stream>>>(counts, binStart, off);
    k_p2_scatter<<<NBLK, 1024, 0, stream>>>(src1, dst1, src2, dst2, counts, binned);
    k_p3_csr    <<<NB, 1024, 0, stream>>>(binned, binStart, off, csr);

    // ---- layer 1 ----
    k_gemm1<<<3125, 256, 0, stream>>>(features, W1, y1b);
    k_pull1<<<12500, 256, 0, stream>>>(y1b, off, csr, b1, attn, x1);

    // ---- layer 2 ----
    k_gemm2<<<1563, 256, 0, stream>>>(x1, W2, y2b);
    k_pull2<<<12500, 256, 0, stream>>>(y2b, off, csr, b2, attn, out);
}